// Round 7
// baseline (178.252 us; speedup 1.0000x reference)
//
#include <hip/hip_runtime.h>

// Shapes: msa [1,128,256,256] f32, pair [1,256,256,128] f32, out same as pair.
// ws: leftT [256 l][4 kk][2 iLow][64 lane][8] bf16  (MFMA A-fragment-direct)
//     rightT same | w3 [16 ck][2 inner][8 w][64 lane][8 e] bf16 (p = w*16+l15)
//     | wB [32 frag: nt*8+ks][64 lane][8 e] bf16 (k_lnproj B-fragment-direct)

typedef float v4f __attribute__((ext_vector_type(4)));
typedef short v8s __attribute__((ext_vector_type(8)));

static __device__ inline unsigned short f2bf(float x) {
    unsigned int u = __builtin_bit_cast(unsigned int, x);
    return (unsigned short)((u + 0x7fffu + ((u >> 16) & 1u)) >> 16);
}

// global->LDS direct copy, 16 B per lane (wave-uniform LDS base + lane*16)
static __device__ inline void gl_lds16(const unsigned short* g, unsigned short* l) {
    __builtin_amdgcn_global_load_lds(
        (const __attribute__((address_space(1))) unsigned int*)g,
        (__attribute__((address_space(3))) unsigned int*)(unsigned long long)l,
        16, 0, 0);
}

// ---------------- one-time weight reformat ----------------
// blocks 0..63: w3 ([ck][inner][8 w][64 lane][8], p = w*16+l15)
// blocks 64..71: wB (k_lnproj B-fragments)
__global__ __launch_bounds__(256) void k_prep(const float* __restrict__ w_out,
                                              const float* __restrict__ wl,
                                              const float* __restrict__ wr,
                                              unsigned short* __restrict__ w3,
                                              unsigned short* __restrict__ wB) {
    const int b = blockIdx.x, t = threadIdx.x;
    unsigned short tmp[8];
    if (b < 64) {
        int tgt = b * 2048 + t * 8;            // linear in w3
        int lane6 = (tgt >> 3) & 63, quad = lane6 >> 4, l15 = lane6 & 15;
        int w = (tgt >> 9) & 7;                // 8 waves
        int inner = (tgt >> 12) & 1, ck = tgt >> 13;
        int p = w * 16 + l15;
        for (int e = 0; e < 8; ++e) {
            int kp = ck * 64 + inner * 32 + quad * 8 + e;   // k' this lane-element feeds
            int j1 = (kp >> 9) & 1, qd = (kp >> 7) & 3, lp = (kp >> 3) & 15;
            int i1 = (kp >> 2) & 1, r = kp & 3;
            int ii = i1 * 16 + qd * 4 + r, jj = j1 * 16 + lp;
            tmp[e] = f2bf(w_out[(ii * 32 + jj) * 128 + p]);
        }
        *(uint4*)&w3[tgt] = *(const uint4*)tmp;
    } else {
        int tgt = (b - 64) * 2048 + t * 8;     // linear in wB (32 frag x 512)
        int frag = tgt >> 9, lane6 = (tgt >> 3) & 63;
        int nt = frag >> 3, ks = frag & 7;
        int quad = lane6 >> 4, l15 = lane6 & 15;
        int c = nt * 16 + l15;
        const float* src = (c < 32) ? wl : wr;
        int cc = c & 31;
        for (int e = 0; e < 8; ++e) {
            int d = ks * 32 + quad * 8 + e;
            tmp[e] = f2bf(src[d * 32 + cc]);
        }
        *(uint4*)&wB[tgt] = *(const uint4*)tmp;
    }
}

// ---------------- LayerNorm + left/right projection ----------------
// grid (256 l, 4 s-quarters), block 256. B-fragments direct from L2 (no wlds).
__global__ __launch_bounds__(256) void k_lnproj(
    const float* __restrict__ msa, const float* __restrict__ gamma, const float* __restrict__ beta,
    const unsigned short* __restrict__ wB, const float* __restrict__ bl, const float* __restrict__ br,
    unsigned short* __restrict__ leftT, unsigned short* __restrict__ rightT) {
    __shared__ unsigned short xb[32 * 264];     // [32 s][256 d + 8 pad]
    __shared__ unsigned short outT[64 * 40];    // [64 c][32 s + 8 pad]

    const int t = threadIdx.x, lane = t & 63, w = t >> 6;
    const int l = blockIdx.x, s0 = blockIdx.y * 32;
    const int quad = lane >> 4, l15 = lane & 15;

    // LayerNorm: wave does 8 rows, reduction batched for 8-way ILP
    float4 g4 = *(const float4*)&gamma[lane * 4];
    float4 be4 = *(const float4*)&beta[lane * 4];
    float4 vr[8]; float s1[8], s2[8];
    for (int r = 0; r < 8; ++r) {
        const float* row = msa + (size_t)((s0 + w * 8 + r) * 256 + l) * 256;
        vr[r] = *(const float4*)&row[lane * 4];
    }
    for (int r = 0; r < 8; ++r) {
        float4 v = vr[r];
        s1[r] = v.x + v.y + v.z + v.w;
        s2[r] = v.x * v.x + v.y * v.y + v.z * v.z + v.w * v.w;
    }
    for (int o = 32; o > 0; o >>= 1)
        for (int r = 0; r < 8; ++r) { s1[r] += __shfl_xor(s1[r], o); s2[r] += __shfl_xor(s2[r], o); }
    for (int r = 0; r < 8; ++r) {
        float mu = s1[r] * (1.f / 256);
        float rs = rsqrtf(s2[r] * (1.f / 256) - mu * mu + 1e-5f);
        float4 v = vr[r];
        ushort4 xs;
        xs.x = f2bf((v.x - mu) * rs * g4.x + be4.x);
        xs.y = f2bf((v.y - mu) * rs * g4.y + be4.y);
        xs.z = f2bf((v.z - mu) * rs * g4.z + be4.z);
        xs.w = f2bf((v.w - mu) * rs * g4.w + be4.w);
        *(ushort4*)&xb[(w * 8 + r) * 264 + lane * 4] = xs;
    }
    __syncthreads();

    // MFMA: M=32 (s), N=64 (c), K=256 — B straight from L2 (frag-direct wB)
    const int mt = w >> 1, ntb = (w & 1) * 2;
    v4f acc[2] = {};
    const int frow = (mt * 16 + l15) * 264;
    const unsigned short* wBp = wB + lane * 8;
#pragma unroll
    for (int ks = 0; ks < 8; ++ks) {
        v8s a = *(const v8s*)&xb[frow + ks * 32 + quad * 8];
        v8s b0 = *(const v8s*)&wBp[(ntb * 8 + ks) * 512];
        v8s b1 = *(const v8s*)&wBp[((ntb + 1) * 8 + ks) * 512];
        acc[0] = __builtin_amdgcn_mfma_f32_16x16x32_bf16(a, b0, acc[0], 0, 0, 0);
        acc[1] = __builtin_amdgcn_mfma_f32_16x16x32_bf16(a, b1, acc[1], 0, 0, 0);
    }

    for (int tn = 0; tn < 2; ++tn) {
        int c = (ntb + tn) * 16 + l15;
        float bias = c < 32 ? bl[c] : br[c - 32];
        float scale = c < 32 ? 1.f : (1.f / 128);
        for (int r = 0; r < 4; ++r)
            outT[c * 40 + mt * 16 + quad * 4 + r] = f2bf((acc[tn][r] + bias) * scale);
    }
    __syncthreads();

    // fragment-direct global writes
    {
        int c = t >> 2, q = t & 3;               // q = sl chunk (8 s each)
        uint4 vv = *(const uint4*)&outT[c * 40 + q * 8];
        int cc = c & 31;
        unsigned short* base = (c < 32) ? leftT : rightT;
        unsigned short* dst = base + l * 4096 + blockIdx.y * 1024
                            + (cc >> 4) * 512 + q * 128 + (cc & 15) * 8;
        *(uint4*)dst = vv;
    }
}

// ---------------- fused outer-product + w_out projection ----------------
// grid (32,64): 8x4 (l,m) = 32 px, 512 threads (8 waves: wm 0..3 x wn 0..1).
// w3 read ONCE per block (512 MB total, halved). LDS 64 KB: stage 48 KB
// aliased under Obuf 64 KB. Register-lean: no long-lived prologue state
// (R3's spill bug). Epilogue: 64B-full-line scatter (R6-proven clean).
__global__ __launch_bounds__(512, 4) void k_outer(
    const unsigned short* __restrict__ leftT, const unsigned short* __restrict__ rightT,
    const unsigned short* __restrict__ w2g, const float* __restrict__ bout,
    const float* __restrict__ pairIn, float* __restrict__ out) {
    __shared__ alignas(16) unsigned short smem[32768];   // 64 KB
    unsigned short* Ah = smem;            // [8 l][2 kl][2 io][64 lane][8] (one kh half, 32 KB)
    unsigned short* Bh = smem + 16384;    // [4 m][...] (16 KB)
    unsigned short* Obuf = smem;          // [32 px][1024 k'] alias, XOR-swizzled

    const int t = threadIdx.x, lane = t & 63, w = t >> 6;
    const int l0 = blockIdx.x * 8, m0 = blockIdx.y * 4;
    const int wm = w & 3, wn = w >> 2;
    const int quad = lane >> 4, l15 = lane & 15;

    const unsigned short* Asrc = leftT + l0 * 4096;
    const unsigned short* Bsrc = rightT + m0 * 4096;

    // ---- phase A: staged halves (kh) via global_load_lds, fragment-direct
    v4f acc[4][4] = {};
    for (int kh = 0; kh < 2; ++kh) {
        if (kh) __syncthreads();          // kh=0 LDS reads done before overwrite
#pragma unroll
        for (int it = 0; it < 4; ++it) {  // A: 32 KB
            int x = (it * 512 + t) * 8;
            gl_lds16(&Asrc[(x >> 11) * 4096 + kh * 2048 + (x & 2047)], &Ah[x]);
        }
#pragma unroll
        for (int it = 0; it < 2; ++it) {  // B: 16 KB
            int x = (it * 512 + t) * 8;
            gl_lds16(&Bsrc[(x >> 11) * 4096 + kh * 2048 + (x & 2047)], &Bh[x]);
        }
        __syncthreads();                  // drains global_load_lds + barrier
#pragma unroll
        for (int kl = 0; kl < 2; ++kl) {
            v8s a[4], bb[4];
#pragma unroll
            for (int i = 0; i < 4; ++i)
                a[i] = *(const v8s*)&Ah[(wm * 2 + (i >> 1)) * 2048 + kl * 1024 + (i & 1) * 512 + lane * 8];
#pragma unroll
            for (int j = 0; j < 4; ++j)
                bb[j] = *(const v8s*)&Bh[(wn * 2 + (j >> 1)) * 2048 + kl * 1024 + (j & 1) * 512 + lane * 8];
#pragma unroll
            for (int i = 0; i < 4; ++i)
#pragma unroll
                for (int j = 0; j < 4; ++j)
                    acc[i][j] = __builtin_amdgcn_mfma_f32_16x16x32_bf16(a[i], bb[j], acc[i][j], 0, 0, 0);
        }
    }
    __syncthreads();   // phase-A LDS reads done before Obuf overwrite

    // ---- issue-early (post-phase-A only: keeps phase-A reg peak low):
    //      w3 frags for ck=0/1 + pairIn + bias; latency hides under scatter
    const unsigned short* wsrc = w2g + w * 512 + lane * 8;
    v8s A0 = *(const v8s*)&wsrc[0];                // (ck=0, inner0)
    v8s A1 = *(const v8s*)&wsrc[4096];             // (ck=0, inner1)
    v8s B0 = *(const v8s*)&wsrc[8192];             // (ck=1, inner0)
    v8s B1 = *(const v8s*)&wsrc[8192 + 4096];      // (ck=1, inner1)
    const int p = w * 16 + l15;
    float bo = bout[p];
    float pf[8];
#pragma unroll
    for (int pm = 0; pm < 2; ++pm)
#pragma unroll
        for (int r = 0; r < 4; ++r) {
            int P = pm * 16 + quad * 4 + r;
            pf[pm * 4 + r] = pairIn[(size_t)((l0 + (P >> 2)) * 256 + (m0 + (P & 3))) * 128 + p];
        }

    // ---- scatter acc -> Obuf, k' = j1*512+quad*128+l15*8+i1*4+r
    for (int a2 = 0; a2 < 2; ++a2)
        for (int b2 = 0; b2 < 2; ++b2) {
            int P = (wm * 2 + a2) * 4 + wn * 2 + b2;
            for (int j1 = 0; j1 < 2; ++j1) {
                unsigned short tmp8[8];
                for (int i1 = 0; i1 < 2; ++i1)
                    for (int r = 0; r < 4; ++r)
                        tmp8[i1 * 4 + r] = f2bf(acc[a2 * 2 + i1][b2 * 2 + j1][r]);
                int pg = (j1 * 64 + lane) ^ (P & 7) ^ ((P & 8) << 3);
                *(uint4*)&Obuf[P * 1024 + pg * 8] = *(const uint4*)tmp8;
            }
        }
    __syncthreads();

    // ---- phase B: P[32][128] = Obuf @ W2. Wave owns p-slice [w*16, w*16+16).
    //      2-deep rolling w3 prefetch; 4 split acc chains.
    v4f aI0[2] = {}, aI1[2] = {};
#pragma unroll
    for (int ck = 0; ck < 16; ck += 2) {
        {   // even ck: A-set
            int g = ck * 8 + quad;
            int ch = ((g ^ (l15 & 7) ^ ((l15 & 8) << 3)) << 3);
            v8s a0 = *(const v8s*)&Obuf[l15 * 1024 + ch];
            v8s a1 = *(const v8s*)&Obuf[(16 + l15) * 1024 + ch];
            aI0[0] = __builtin_amdgcn_mfma_f32_16x16x32_bf16(a0, A0, aI0[0], 0, 0, 0);
            aI0[1] = __builtin_amdgcn_mfma_f32_16x16x32_bf16(a1, A0, aI0[1], 0, 0, 0);
            int g2 = ck * 8 + 4 + quad;
            int ch2 = ((g2 ^ (l15 & 7) ^ ((l15 & 8) << 3)) << 3);
            v8s b0 = *(const v8s*)&Obuf[l15 * 1024 + ch2];
            v8s b1 = *(const v8s*)&Obuf[(16 + l15) * 1024 + ch2];
            aI1[0] = __builtin_amdgcn_mfma_f32_16x16x32_bf16(b0, A1, aI1[0], 0, 0, 0);
            aI1[1] = __builtin_amdgcn_mfma_f32_16x16x32_bf16(b1, A1, aI1[1], 0, 0, 0);
            if (ck + 2 < 16) {
                const unsigned short* nx = wsrc + (ck + 2) * 8192;
                A0 = *(const v8s*)&nx[0];
                A1 = *(const v8s*)&nx[4096];
            }
        }
        {   // odd ck+1: B-set
            int g = (ck + 1) * 8 + quad;
            int ch = ((g ^ (l15 & 7) ^ ((l15 & 8) << 3)) << 3);
            v8s a0 = *(const v8s*)&Obuf[l15 * 1024 + ch];
            v8s a1 = *(const v8s*)&Obuf[(16 + l15) * 1024 + ch];
            aI0[0] = __builtin_amdgcn_mfma_f32_16x16x32_bf16(a0, B0, aI0[0], 0, 0, 0);
            aI0[1] = __builtin_amdgcn_mfma_f32_16x16x32_bf16(a1, B0, aI0[1], 0, 0, 0);
            int g2 = (ck + 1) * 8 + 4 + quad;
            int ch2 = ((g2 ^ (l15 & 7) ^ ((l15 & 8) << 3)) << 3);
            v8s b0 = *(const v8s*)&Obuf[l15 * 1024 + ch2];
            v8s b1 = *(const v8s*)&Obuf[(16 + l15) * 1024 + ch2];
            aI1[0] = __builtin_amdgcn_mfma_f32_16x16x32_bf16(b0, B1, aI1[0], 0, 0, 0);
            aI1[1] = __builtin_amdgcn_mfma_f32_16x16x32_bf16(b1, B1, aI1[1], 0, 0, 0);
            if (ck + 3 < 16) {
                const unsigned short* nx = wsrc + (ck + 3) * 8192;
                B0 = *(const v8s*)&nx[0];
                B1 = *(const v8s*)&nx[4096];
            }
        }
    }

    // ---- epilogue: out = pair + P + b_out (each 64B line fully covered by one instr)
#pragma unroll
    for (int pm = 0; pm < 2; ++pm)
#pragma unroll
        for (int r = 0; r < 4; ++r) {
            int P = pm * 16 + quad * 4 + r;
            size_t idx = (size_t)((l0 + (P >> 2)) * 256 + (m0 + (P & 3))) * 128 + p;
            out[idx] = pf[pm * 4 + r] + bo + aI0[pm][r] + aI1[pm][r];
        }
}

extern "C" void kernel_launch(void* const* d_in, const int* in_sizes, int n_in,
                              void* d_out, int out_size, void* d_ws, size_t ws_size,
                              hipStream_t stream) {
    const float* msa   = (const float*)d_in[0];
    const float* pairI = (const float*)d_in[1];
    const float* gamma = (const float*)d_in[4];
    const float* beta  = (const float*)d_in[5];
    const float* wl    = (const float*)d_in[6];
    const float* bl    = (const float*)d_in[7];
    const float* wr    = (const float*)d_in[8];
    const float* br    = (const float*)d_in[9];
    const float* wout  = (const float*)d_in[10];
    const float* bout  = (const float*)d_in[11];
    float* out = (float*)d_out;

    unsigned short* leftT  = (unsigned short*)d_ws;
    unsigned short* rightT = leftT + 256 * 32 * 128;
    unsigned short* w3     = rightT + 256 * 32 * 128;
    unsigned short* wB     = w3 + 131072;

    k_prep<<<dim3(72), 256, 0, stream>>>(wout, wl, wr, w3, wB);
    k_lnproj<<<dim3(256, 4), 256, 0, stream>>>(msa, gamma, beta, wB, bl, br, leftT, rightT);
    k_outer<<<dim3(32, 64), 512, 0, stream>>>(leftT, rightT, w3, bout, pairI, out);
}

// Round 8
// 161.630 us; speedup vs baseline: 1.1028x; 1.1028x over previous
//
#include <hip/hip_runtime.h>

// Shapes: msa [1,128,256,256] f32, pair [1,256,256,128] f32, out same as pair.
// ws: leftT [256 l][4 kk][2 iLow][64 lane][8] bf16  (MFMA A-fragment-direct)
//     rightT same | w3 [16 ck][2 inner][8 w][64 lane][8 e] bf16 (p = w*16+l15)
//     | wB [32 frag: nt*8+ks][64 lane][8 e] bf16 (k_lnproj B-fragment-direct)

typedef float v4f __attribute__((ext_vector_type(4)));
typedef short v8s __attribute__((ext_vector_type(8)));

static __device__ inline unsigned short f2bf(float x) {
    unsigned int u = __builtin_bit_cast(unsigned int, x);
    return (unsigned short)((u + 0x7fffu + ((u >> 16) & 1u)) >> 16);
}

// global->LDS direct copy, 16 B per lane (wave-uniform LDS base + lane*16)
static __device__ inline void gl_lds16(const unsigned short* g, unsigned short* l) {
    __builtin_amdgcn_global_load_lds(
        (const __attribute__((address_space(1))) unsigned int*)g,
        (__attribute__((address_space(3))) unsigned int*)(unsigned long long)l,
        16, 0, 0);
}

// ---------------- one-time weight reformat ----------------
// blocks 0..63: w3 ([ck][inner][8 w][64 lane][8], p = w*16+l15)
// blocks 64..71: wB (k_lnproj B-fragments)
__global__ __launch_bounds__(256) void k_prep(const float* __restrict__ w_out,
                                              const float* __restrict__ wl,
                                              const float* __restrict__ wr,
                                              unsigned short* __restrict__ w3,
                                              unsigned short* __restrict__ wB) {
    const int b = blockIdx.x, t = threadIdx.x;
    unsigned short tmp[8];
    if (b < 64) {
        int tgt = b * 2048 + t * 8;            // linear in w3
        int lane6 = (tgt >> 3) & 63, quad = lane6 >> 4, l15 = lane6 & 15;
        int w = (tgt >> 9) & 7;                // 8 waves
        int inner = (tgt >> 12) & 1, ck = tgt >> 13;
        int p = w * 16 + l15;
        for (int e = 0; e < 8; ++e) {
            int kp = ck * 64 + inner * 32 + quad * 8 + e;   // k' this lane-element feeds
            int j1 = (kp >> 9) & 1, qd = (kp >> 7) & 3, lp = (kp >> 3) & 15;
            int i1 = (kp >> 2) & 1, r = kp & 3;
            int ii = i1 * 16 + qd * 4 + r, jj = j1 * 16 + lp;
            tmp[e] = f2bf(w_out[(ii * 32 + jj) * 128 + p]);
        }
        *(uint4*)&w3[tgt] = *(const uint4*)tmp;
    } else {
        int tgt = (b - 64) * 2048 + t * 8;     // linear in wB (32 frag x 512)
        int frag = tgt >> 9, lane6 = (tgt >> 3) & 63;
        int nt = frag >> 3, ks = frag & 7;
        int quad = lane6 >> 4, l15 = lane6 & 15;
        int c = nt * 16 + l15;
        const float* src = (c < 32) ? wl : wr;
        int cc = c & 31;
        for (int e = 0; e < 8; ++e) {
            int d = ks * 32 + quad * 8 + e;
            tmp[e] = f2bf(src[d * 32 + cc]);
        }
        *(uint4*)&wB[tgt] = *(const uint4*)tmp;
    }
}

// ---------------- LayerNorm + left/right projection ----------------
// grid (256 l, 4 s-quarters), block 256. B-fragments direct from L2 (no wlds).
__global__ __launch_bounds__(256) void k_lnproj(
    const float* __restrict__ msa, const float* __restrict__ gamma, const float* __restrict__ beta,
    const unsigned short* __restrict__ wB, const float* __restrict__ bl, const float* __restrict__ br,
    unsigned short* __restrict__ leftT, unsigned short* __restrict__ rightT) {
    __shared__ unsigned short xb[32 * 264];     // [32 s][256 d + 8 pad]
    __shared__ unsigned short outT[64 * 40];    // [64 c][32 s + 8 pad]

    const int t = threadIdx.x, lane = t & 63, w = t >> 6;
    const int l = blockIdx.x, s0 = blockIdx.y * 32;
    const int quad = lane >> 4, l15 = lane & 15;

    // LayerNorm: wave does 8 rows, reduction batched for 8-way ILP
    float4 g4 = *(const float4*)&gamma[lane * 4];
    float4 be4 = *(const float4*)&beta[lane * 4];
    float4 vr[8]; float s1[8], s2[8];
    for (int r = 0; r < 8; ++r) {
        const float* row = msa + (size_t)((s0 + w * 8 + r) * 256 + l) * 256;
        vr[r] = *(const float4*)&row[lane * 4];
    }
    for (int r = 0; r < 8; ++r) {
        float4 v = vr[r];
        s1[r] = v.x + v.y + v.z + v.w;
        s2[r] = v.x * v.x + v.y * v.y + v.z * v.z + v.w * v.w;
    }
    for (int o = 32; o > 0; o >>= 1)
        for (int r = 0; r < 8; ++r) { s1[r] += __shfl_xor(s1[r], o); s2[r] += __shfl_xor(s2[r], o); }
    for (int r = 0; r < 8; ++r) {
        float mu = s1[r] * (1.f / 256);
        float rs = rsqrtf(s2[r] * (1.f / 256) - mu * mu + 1e-5f);
        float4 v = vr[r];
        ushort4 xs;
        xs.x = f2bf((v.x - mu) * rs * g4.x + be4.x);
        xs.y = f2bf((v.y - mu) * rs * g4.y + be4.y);
        xs.z = f2bf((v.z - mu) * rs * g4.z + be4.z);
        xs.w = f2bf((v.w - mu) * rs * g4.w + be4.w);
        *(ushort4*)&xb[(w * 8 + r) * 264 + lane * 4] = xs;
    }
    __syncthreads();

    // MFMA: M=32 (s), N=64 (c), K=256 — B straight from L2 (frag-direct wB)
    const int mt = w >> 1, ntb = (w & 1) * 2;
    v4f acc[2] = {};
    const int frow = (mt * 16 + l15) * 264;
    const unsigned short* wBp = wB + lane * 8;
#pragma unroll
    for (int ks = 0; ks < 8; ++ks) {
        v8s a = *(const v8s*)&xb[frow + ks * 32 + quad * 8];
        v8s b0 = *(const v8s*)&wBp[(ntb * 8 + ks) * 512];
        v8s b1 = *(const v8s*)&wBp[((ntb + 1) * 8 + ks) * 512];
        acc[0] = __builtin_amdgcn_mfma_f32_16x16x32_bf16(a, b0, acc[0], 0, 0, 0);
        acc[1] = __builtin_amdgcn_mfma_f32_16x16x32_bf16(a, b1, acc[1], 0, 0, 0);
    }

    for (int tn = 0; tn < 2; ++tn) {
        int c = (ntb + tn) * 16 + l15;
        float bias = c < 32 ? bl[c] : br[c - 32];
        float scale = c < 32 ? 1.f : (1.f / 128);
        for (int r = 0; r < 4; ++r)
            outT[c * 40 + mt * 16 + quad * 4 + r] = f2bf((acc[tn][r] + bias) * scale);
    }
    __syncthreads();

    // fragment-direct global writes
    {
        int c = t >> 2, q = t & 3;               // q = sl chunk (8 s each)
        uint4 vv = *(const uint4*)&outT[c * 40 + q * 8];
        int cc = c & 31;
        unsigned short* base = (c < 32) ? leftT : rightT;
        unsigned short* dst = base + l * 4096 + blockIdx.y * 1024
                            + (cc >> 4) * 512 + q * 128 + (cc & 15) * 8;
        *(uint4*)dst = vv;
    }
}

// ---------------- fused outer-product + w_out projection ----------------
// grid (32,64): 8x4 (l,m) = 32 px, 512 threads (8 waves). w3 read ONCE per
// block. Pbuf LDS transpose -> full-512B-line pair/out traffic (fixes the
// 64B partial-line amplification seen as WRITE_SIZE 82 MB in R4/R7).
__global__ __launch_bounds__(512, 4) void k_outer(
    const unsigned short* __restrict__ leftT, const unsigned short* __restrict__ rightT,
    const unsigned short* __restrict__ w2g, const float* __restrict__ bout,
    const float* __restrict__ pairIn, float* __restrict__ out) {
    __shared__ alignas(16) unsigned short smem[32768];   // 64 KB
    unsigned short* Ah = smem;            // staging (one kh half): A 32 KB
    unsigned short* Bh = smem + 16384;    // B 16 KB
    unsigned short* Obuf = smem;          // [32 px][1024 k'] alias, XOR-swizzled
    float* Pbuf = (float*)smem;           // [32 px][132] f32 alias (17 KB)

    const int t = threadIdx.x, lane = t & 63, w = t >> 6;
    const int l0 = blockIdx.x * 8, m0 = blockIdx.y * 4;
    const int wm = w & 3, wn = w >> 2;
    const int quad = lane >> 4, l15 = lane & 15;

    const unsigned short* Asrc = leftT + l0 * 4096;
    const unsigned short* Bsrc = rightT + m0 * 4096;

    // ---- phase A: staged halves (kh) via global_load_lds, fragment-direct
    v4f acc[4][4] = {};
    for (int kh = 0; kh < 2; ++kh) {
        if (kh) __syncthreads();          // kh=0 LDS reads done before overwrite
#pragma unroll
        for (int it = 0; it < 4; ++it) {  // A: 32 KB
            int x = (it * 512 + t) * 8;
            gl_lds16(&Asrc[(x >> 11) * 4096 + kh * 2048 + (x & 2047)], &Ah[x]);
        }
#pragma unroll
        for (int it = 0; it < 2; ++it) {  // B: 16 KB
            int x = (it * 512 + t) * 8;
            gl_lds16(&Bsrc[(x >> 11) * 4096 + kh * 2048 + (x & 2047)], &Bh[x]);
        }
        __syncthreads();                  // drains global_load_lds + barrier
#pragma unroll
        for (int kl = 0; kl < 2; ++kl) {
            v8s a[4], bb[4];
#pragma unroll
            for (int i = 0; i < 4; ++i)
                a[i] = *(const v8s*)&Ah[(wm * 2 + (i >> 1)) * 2048 + kl * 1024 + (i & 1) * 512 + lane * 8];
#pragma unroll
            for (int j = 0; j < 4; ++j)
                bb[j] = *(const v8s*)&Bh[(wn * 2 + (j >> 1)) * 2048 + kl * 1024 + (j & 1) * 512 + lane * 8];
#pragma unroll
            for (int i = 0; i < 4; ++i)
#pragma unroll
                for (int j = 0; j < 4; ++j)
                    acc[i][j] = __builtin_amdgcn_mfma_f32_16x16x32_bf16(a[i], bb[j], acc[i][j], 0, 0, 0);
        }
    }
    __syncthreads();   // phase-A LDS reads done before Obuf overwrite

    // ---- issue-early: w3 frags for ck=0/1 + bias (hide under scatter)
    const unsigned short* wsrc = w2g + w * 512 + lane * 8;
    v8s A0 = *(const v8s*)&wsrc[0];                // (ck=0, inner0)
    v8s A1 = *(const v8s*)&wsrc[4096];             // (ck=0, inner1)
    v8s B0 = *(const v8s*)&wsrc[8192];             // (ck=1, inner0)
    v8s B1 = *(const v8s*)&wsrc[8192 + 4096];      // (ck=1, inner1)
    const int p = w * 16 + l15;
    float bo = bout[p];

    // ---- scatter acc -> Obuf, k' = j1*512+quad*128+l15*8+i1*4+r
    for (int a2 = 0; a2 < 2; ++a2)
        for (int b2 = 0; b2 < 2; ++b2) {
            int P = (wm * 2 + a2) * 4 + wn * 2 + b2;
            for (int j1 = 0; j1 < 2; ++j1) {
                unsigned short tmp8[8];
                for (int i1 = 0; i1 < 2; ++i1)
                    for (int r = 0; r < 4; ++r)
                        tmp8[i1 * 4 + r] = f2bf(acc[a2 * 2 + i1][b2 * 2 + j1][r]);
                int pg = (j1 * 64 + lane) ^ (P & 7) ^ ((P & 8) << 3);
                *(uint4*)&Obuf[P * 1024 + pg * 8] = *(const uint4*)tmp8;
            }
        }
    __syncthreads();

    // ---- phase B: P[32][128] = Obuf @ W2. Wave owns p-slice [w*16, w*16+16).
    //      2-deep rolling w3 prefetch; 4 split acc chains.
    v4f aI0[2] = {}, aI1[2] = {};
#pragma unroll
    for (int ck = 0; ck < 16; ck += 2) {
        {   // even ck: A-set
            int g = ck * 8 + quad;
            int ch = ((g ^ (l15 & 7) ^ ((l15 & 8) << 3)) << 3);
            v8s a0 = *(const v8s*)&Obuf[l15 * 1024 + ch];
            v8s a1 = *(const v8s*)&Obuf[(16 + l15) * 1024 + ch];
            aI0[0] = __builtin_amdgcn_mfma_f32_16x16x32_bf16(a0, A0, aI0[0], 0, 0, 0);
            aI0[1] = __builtin_amdgcn_mfma_f32_16x16x32_bf16(a1, A0, aI0[1], 0, 0, 0);
            int g2 = ck * 8 + 4 + quad;
            int ch2 = ((g2 ^ (l15 & 7) ^ ((l15 & 8) << 3)) << 3);
            v8s b0 = *(const v8s*)&Obuf[l15 * 1024 + ch2];
            v8s b1 = *(const v8s*)&Obuf[(16 + l15) * 1024 + ch2];
            aI1[0] = __builtin_amdgcn_mfma_f32_16x16x32_bf16(b0, A1, aI1[0], 0, 0, 0);
            aI1[1] = __builtin_amdgcn_mfma_f32_16x16x32_bf16(b1, A1, aI1[1], 0, 0, 0);
            if (ck + 2 < 16) {
                const unsigned short* nx = wsrc + (ck + 2) * 8192;
                A0 = *(const v8s*)&nx[0];
                A1 = *(const v8s*)&nx[4096];
            }
        }
        {   // odd ck+1: B-set
            int g = (ck + 1) * 8 + quad;
            int ch = ((g ^ (l15 & 7) ^ ((l15 & 8) << 3)) << 3);
            v8s a0 = *(const v8s*)&Obuf[l15 * 1024 + ch];
            v8s a1 = *(const v8s*)&Obuf[(16 + l15) * 1024 + ch];
            aI0[0] = __builtin_amdgcn_mfma_f32_16x16x32_bf16(a0, B0, aI0[0], 0, 0, 0);
            aI0[1] = __builtin_amdgcn_mfma_f32_16x16x32_bf16(a1, B0, aI0[1], 0, 0, 0);
            int g2 = (ck + 1) * 8 + 4 + quad;
            int ch2 = ((g2 ^ (l15 & 7) ^ ((l15 & 8) << 3)) << 3);
            v8s b0 = *(const v8s*)&Obuf[l15 * 1024 + ch2];
            v8s b1 = *(const v8s*)&Obuf[(16 + l15) * 1024 + ch2];
            aI1[0] = __builtin_amdgcn_mfma_f32_16x16x32_bf16(b0, B1, aI1[0], 0, 0, 0);
            aI1[1] = __builtin_amdgcn_mfma_f32_16x16x32_bf16(b1, B1, aI1[1], 0, 0, 0);
            if (ck + 3 < 16) {
                const unsigned short* nx = wsrc + (ck + 3) * 8192;
                B0 = *(const v8s*)&nx[0];
                B1 = *(const v8s*)&nx[4096];
            }
        }
    }

    // ---- issue pairIn loads now (wave's 4 full rows; overlap Pbuf round-trip)
    const float* psrc = pairIn + (size_t)((l0 + w) * 256 + m0) * 128 + lane * 2;
    float2 pp[4];
#pragma unroll
    for (int sub = 0; sub < 4; ++sub) pp[sub] = *(const float2*)&psrc[sub * 128];

    __syncthreads();   // all Obuf reads done before Pbuf overwrite

    // ---- transpose through LDS: Pbuf[P][p] = acc2 + bias (2-way conflicts, free)
#pragma unroll
    for (int pm = 0; pm < 2; ++pm)
#pragma unroll
        for (int r = 0; r < 4; ++r) {
            int P = pm * 16 + quad * 4 + r;
            Pbuf[P * 132 + p] = (pm ? aI0[1][r] + aI1[1][r] : aI0[0][r] + aI1[0][r]) + bo;
        }
    __syncthreads();

    // ---- epilogue: wave writes its 4 FULL 512B rows (line-merged traffic)
    float* odst = out + (size_t)((l0 + w) * 256 + m0) * 128 + lane * 2;
#pragma unroll
    for (int sub = 0; sub < 4; ++sub) {
        int P = w * 4 + sub;
        float2 pv = *(const float2*)&Pbuf[P * 132 + lane * 2];
        float2 ov;
        ov.x = pp[sub].x + pv.x;
        ov.y = pp[sub].y + pv.y;
        *(float2*)&odst[sub * 128] = ov;
    }
}

extern "C" void kernel_launch(void* const* d_in, const int* in_sizes, int n_in,
                              void* d_out, int out_size, void* d_ws, size_t ws_size,
                              hipStream_t stream) {
    const float* msa   = (const float*)d_in[0];
    const float* pairI = (const float*)d_in[1];
    const float* gamma = (const float*)d_in[4];
    const float* beta  = (const float*)d_in[5];
    const float* wl    = (const float*)d_in[6];
    const float* bl    = (const float*)d_in[7];
    const float* wr    = (const float*)d_in[8];
    const float* br    = (const float*)d_in[9];
    const float* wout  = (const float*)d_in[10];
    const float* bout  = (const float*)d_in[11];
    float* out = (float*)d_out;

    unsigned short* leftT  = (unsigned short*)d_ws;
    unsigned short* rightT = leftT + 256 * 32 * 128;
    unsigned short* w3     = rightT + 256 * 32 * 128;
    unsigned short* wB     = w3 + 131072;

    k_prep<<<dim3(72), 256, 0, stream>>>(wout, wl, wr, w3, wB);
    k_lnproj<<<dim3(256, 4), 256, 0, stream>>>(msa, gamma, beta, wB, bl, br, leftT, rightT);
    k_outer<<<dim3(32, 64), 512, 0, stream>>>(leftT, rightT, w3, bout, pairI, out);
}